// Round 5
// baseline (1170.077 us; speedup 1.0000x reference)
//
#include <hip/hip_runtime.h>
#include <math.h>
#include <stdint.h>

#define NTOK   16384
#define DIM    4096
#define NEXP   256
#define TOPKG  4
#define TOPK   8
#define NSPLIT 4
#define KCHUNK (DIM / NSPLIT)   // 1024
#define BM     128
#define BK     32
#define NSTEPS (KCHUNK / BK)    // 32

typedef float v4f   __attribute__((ext_vector_type(4)));
typedef short short8 __attribute__((ext_vector_type(8)));

__device__ inline unsigned short f2bf(float x) {           // round-to-nearest-even
    unsigned u = __float_as_uint(x);
    return (unsigned short)((u + 0x7fffu + ((u >> 16) & 1u)) >> 16);
}
__device__ inline float bf2f(unsigned short h) {
    return __uint_as_float(((unsigned)h) << 16);
}
// 4-slot XOR swizzle within a 64B row (involution; verified R2: conflicts=0)
__device__ inline int swz4(int row, int slot) { return slot ^ ((row >> 1) & 3); }

// ---- W fp32 -> bf16 (hi, lo) row-major [256][4096], done once per call ----
__global__ __launch_bounds__(256) void wprep(const float* __restrict__ W,
                                             unsigned short* __restrict__ Wh,
                                             unsigned short* __restrict__ Wl) {
    int i = (blockIdx.x * 256 + threadIdx.x) * 4;
    float4 v = *(const float4*)(W + i);
    ushort4 h, l;
    h.x = f2bf(v.x); l.x = f2bf(v.x - bf2f(h.x));
    h.y = f2bf(v.y); l.y = f2bf(v.y - bf2f(h.y));
    h.z = f2bf(v.z); l.z = f2bf(v.z - bf2f(h.z));
    h.w = f2bf(v.w); l.w = f2bf(v.w - bf2f(h.w));
    *(ushort4*)(Wh + i) = h;
    *(ushort4*)(Wl + i) = l;
}

// ---- GEMM: P[z][t][e] = sum_{k in chunk z} X[t,k] W[e,k], bf16x2 3-pass MFMA ----
// Direct-A structure: A fragments load straight from global into registers
// (no A LDS round-trip, no A ds_write/ds_read on the port), convert hi/lo
// in-register. LDS = B-only 64 KB dbuf -> 2 destaggered blocks/CU;
// acc[4][4]=32 AGPR, launch_bounds(512,4) forces <=128 regs -> 16 waves/CU.
__global__ __launch_bounds__(512, 4) void gate_gemm(const float* __restrict__ X,
                                                    const unsigned short* __restrict__ Wh,
                                                    const unsigned short* __restrict__ Wl,
                                                    float* __restrict__ P) {
    __shared__ __align__(16) unsigned short Bh[2][NEXP * BK];  // 2 x 16 KB
    __shared__ __align__(16) unsigned short Bl[2][NEXP * BK];  // -> 64 KB total

    const int t  = threadIdx.x;            // 0..511
    const int bm = blockIdx.x * BM;
    const int z  = blockIdx.y;
    const int k0 = z * KCHUNK;

    const int l  = t & 63;
    const int w  = t >> 6;                 // 0..7
    const int wr = w >> 2;                 // 0..1: 64-token row half
    const int wc = w & 3;                  // 0..3: 64-expert column quarter
    const int lm = l & 15;
    const int lq = l >> 4;                 // 16B k-slot (0..3)

    // per-lane A source: row bm + wr*64 + r*16 + lm, k-slot lq*8
    const float* xbase = X + (size_t)(bm + wr * 64 + lm) * DIM + k0 + lq * 8;

    v4f acc[4][4] = {};

    // ---- prologue: stage B(0) into buffer 0 ----
#pragma unroll
    for (int i = 0; i < 2; ++i) {
        int flat = i * 512 + t;            // 0..1023
        int e = flat >> 2, qq = flat & 3;
        const unsigned short* gh = Wh + (size_t)e * DIM + k0 + swz4(e, qq) * 8;
        const unsigned short* gl = Wl + (size_t)e * DIM + k0 + swz4(e, qq) * 8;
        __builtin_amdgcn_global_load_lds(
            (const __attribute__((address_space(1))) unsigned int*)gh,
            (__attribute__((address_space(3))) unsigned int*)&Bh[0][flat * 8], 16, 0, 0);
        __builtin_amdgcn_global_load_lds(
            (const __attribute__((address_space(1))) unsigned int*)gl,
            (__attribute__((address_space(3))) unsigned int*)&Bl[0][flat * 8], 16, 0, 0);
    }
    __syncthreads();   // B(0) visible

    int cur = 0;
    for (int s = 0; s < NSTEPS; ++s) {
        const int nxt = cur ^ 1;
        const bool pf = (s + 1 < NSTEPS);

        // ---- (1) A fp32 loads for THIS step (oldest in vmcnt queue) ----
        float4 a0[4], a1[4];
#pragma unroll
        for (int r = 0; r < 4; ++r) {
            const float* p = xbase + (size_t)r * 16 * DIM + s * BK;
            a0[r] = *(const float4*)p;
            a1[r] = *(const float4*)(p + 4);
        }

        // ---- (2) B(s+1) gl_lds prefetch into nxt (drained at step-end sync) ----
        if (pf) {
            const int krn = (s + 1) * BK;
#pragma unroll
            for (int i = 0; i < 2; ++i) {
                int flat = i * 512 + t;
                int e = flat >> 2, qq = flat & 3;
                const unsigned short* gh = Wh + (size_t)e * DIM + k0 + krn + swz4(e, qq) * 8;
                const unsigned short* gl = Wl + (size_t)e * DIM + k0 + krn + swz4(e, qq) * 8;
                __builtin_amdgcn_global_load_lds(
                    (const __attribute__((address_space(1))) unsigned int*)gh,
                    (__attribute__((address_space(3))) unsigned int*)&Bh[nxt][flat * 8], 16, 0, 0);
                __builtin_amdgcn_global_load_lds(
                    (const __attribute__((address_space(1))) unsigned int*)gl,
                    (__attribute__((address_space(3))) unsigned int*)&Bl[nxt][flat * 8], 16, 0, 0);
            }
        }
        __builtin_amdgcn_sched_barrier(0);   // keep load-issue above compute

        // ---- (3) B fragments from cur ----
        short8 bh[4], bl[4];
#pragma unroll
        for (int c = 0; c < 4; ++c) {
            int e = wc * 64 + c * 16 + lm;
            bh[c] = *(const short8*)&Bh[cur][e * BK + swz4(e, lq) * 8];
            bl[c] = *(const short8*)&Bl[cur][e * BK + swz4(e, lq) * 8];
        }

        // ---- (4) convert A in-register (identical hi/lo math as before) ----
        short8 ah[4], al[4];
#pragma unroll
        for (int r = 0; r < 4; ++r) {
#pragma unroll
            for (int j = 0; j < 8; ++j) {
                float x = (j < 4) ? ((const float*)&a0[r])[j] : ((const float*)&a1[r])[j - 4];
                unsigned short h = f2bf(x);
                ah[r][j] = (short)h;
                al[r][j] = (short)f2bf(x - bf2f(h));
            }
        }

        // ---- (5) 48 MFMA ----
        __builtin_amdgcn_s_setprio(1);
#pragma unroll
        for (int r = 0; r < 4; ++r)
#pragma unroll
            for (int c = 0; c < 4; ++c) {
                acc[r][c] = __builtin_amdgcn_mfma_f32_16x16x32_bf16(ah[r], bh[c], acc[r][c], 0, 0, 0);
                acc[r][c] = __builtin_amdgcn_mfma_f32_16x16x32_bf16(ah[r], bl[c], acc[r][c], 0, 0, 0);
                acc[r][c] = __builtin_amdgcn_mfma_f32_16x16x32_bf16(al[r], bh[c], acc[r][c], 0, 0, 0);
            }
        __builtin_amdgcn_s_setprio(0);

        __syncthreads();   // one drain/step: publishes B(s+1), protects cur
        cur = nxt;
    }

    // epilogue: C/D layout col=lane&15, row=lq*4+reg (verified m89/m91)
    float* Pb = P + ((size_t)z * NTOK + bm) * NEXP;
#pragma unroll
    for (int r = 0; r < 4; ++r)
#pragma unroll
        for (int c = 0; c < 4; ++c)
#pragma unroll
            for (int g = 0; g < 4; ++g)
                Pb[(size_t)(wr * 64 + r * 16 + lq * 4 + g) * NEXP + wc * 64 + c * 16 + lm] = acc[r][c][g];
}

// ---- fused reduce (4 partials, fixed order) + routing: one wave per token ----
__global__ __launch_bounds__(256) void gate_route(const float* __restrict__ P,
                                                  float* __restrict__ outw,
                                                  float* __restrict__ outi) {
    const int lane = threadIdx.x & 63;
    const int tok  = (blockIdx.x * blockDim.x + threadIdx.x) >> 6;
    if (tok >= NTOK) return;

    float l[4] = {0.f, 0.f, 0.f, 0.f};
#pragma unroll
    for (int z = 0; z < NSPLIT; ++z) {   // fixed order: deterministic across runs
        float4 v = *(const float4*)(P + ((size_t)z * NTOK + tok) * NEXP + lane * 4);
        l[0] += v.x; l[1] += v.y; l[2] += v.z; l[3] += v.w;
    }

    float lmax = fmaxf(fmaxf(l[0], l[1]), fmaxf(l[2], l[3]));
    float m = lmax;
#pragma unroll
    for (int o = 32; o; o >>= 1) m = fmaxf(m, __shfl_xor(m, o));

    float s = __expf(l[0] - m) + __expf(l[1] - m) + __expf(l[2] - m) + __expf(l[3] - m);
#pragma unroll
    for (int o = 32; o; o >>= 1) s += __shfl_xor(s, o);

    float gm = lmax;
#pragma unroll
    for (int o = 4; o; o >>= 1) gm = fmaxf(gm, __shfl_xor(gm, o));

    const int g = lane >> 3;
    int rank = 0;
#pragma unroll
    for (int gg = 0; gg < 8; ++gg) {
        float vg = __shfl(gm, gg * 8);
        rank += (vg > gm) || (vg == gm && gg < g);
    }
    const bool allowed = rank < TOPKG;

    float mv[4];
#pragma unroll
    for (int j = 0; j < 4; ++j) mv[j] = allowed ? l[j] : -INFINITY;

    float wsel = 0.0f;
    int   isel = 0;

    for (int k = 0; k < TOPK; ++k) {
        float bv = mv[0];
        int   bi = lane * 4;
        if (mv[1] > bv) { bv = mv[1]; bi = lane * 4 + 1; }
        if (mv[2] > bv) { bv = mv[2]; bi = lane * 4 + 2; }
        if (mv[3] > bv) { bv = mv[3]; bi = lane * 4 + 3; }
#pragma unroll
        for (int o = 32; o; o >>= 1) {
            float ov = __shfl_xor(bv, o);
            int   oi = __shfl_xor(bi, o);
            if (ov > bv || (ov == bv && oi < bi)) { bv = ov; bi = oi; }
        }
        if (lane == k) { wsel = __expf(bv - m) / s; isel = bi; }
        if ((bi >> 2) == lane) mv[bi & 3] = -INFINITY;
    }

    if (lane < TOPK) {
        outw[(size_t)tok * TOPK + lane] = wsel;
        outi[(size_t)tok * TOPK + lane] = (float)isel;
    }
}

extern "C" void kernel_launch(void* const* d_in, const int* in_sizes, int n_in,
                              void* d_out, int out_size, void* d_ws, size_t ws_size,
                              hipStream_t stream) {
    const float* x  = (const float*)d_in[0];   // [16384, 4096]
    const float* wt = (const float*)d_in[1];   // [256, 4096]

    // ws layout: partials [4][16384][256] f32 (64 MB) | Wh (2 MB) | Wl (2 MB)
    float* P = (float*)d_ws;
    unsigned short* Wh = (unsigned short*)((char*)d_ws + (size_t)NSPLIT * NTOK * NEXP * 4);
    unsigned short* Wl = Wh + (size_t)NEXP * DIM;

    float* outw = (float*)d_out;
    float* outi = (float*)d_out + (size_t)NTOK * TOPK;

    wprep<<<(NEXP * DIM) / (256 * 4), 256, 0, stream>>>(wt, Wh, Wl);

    dim3 ggrid(NTOK / BM, NSPLIT);   // (128, 4) = 512 blocks, 2/CU, destaggered
    gate_gemm<<<ggrid, 512, 0, stream>>>(x, Wh, Wl, P);

    gate_route<<<(NTOK * 64) / 256, 256, 0, stream>>>(P, outw, outi);
}

// Round 6
// 429.794 us; speedup vs baseline: 2.7224x; 2.7224x over previous
//
#include <hip/hip_runtime.h>
#include <math.h>
#include <stdint.h>

#define NTOK   16384
#define DIM    4096
#define NEXP   256
#define TOPKG  4
#define TOPK   8
#define NSPLIT 4
#define KCHUNK (DIM / NSPLIT)   // 1024
#define BM     256
#define BK     32
#define NSTEPS (KCHUNK / BK)    // 32

typedef float v4f   __attribute__((ext_vector_type(4)));
typedef short short8 __attribute__((ext_vector_type(8)));

__device__ inline unsigned short f2bf(float x) {           // round-to-nearest-even
    unsigned u = __float_as_uint(x);
    return (unsigned short)((u + 0x7fffu + ((u >> 16) & 1u)) >> 16);
}
__device__ inline float bf2f(unsigned short h) {
    return __uint_as_float(((unsigned)h) << 16);
}
// 4-slot XOR swizzle within a 64B row (involution; verified R2: conflicts=0)
__device__ inline int swz4(int row, int slot) { return slot ^ ((row >> 1) & 3); }

// ---- W fp32 -> bf16 (hi, lo) row-major [256][4096], done once per call ----
__global__ __launch_bounds__(256) void wprep(const float* __restrict__ W,
                                             unsigned short* __restrict__ Wh,
                                             unsigned short* __restrict__ Wl) {
    int i = (blockIdx.x * 256 + threadIdx.x) * 4;
    float4 v = *(const float4*)(W + i);
    ushort4 h, l;
    h.x = f2bf(v.x); l.x = f2bf(v.x - bf2f(h.x));
    h.y = f2bf(v.y); l.y = f2bf(v.y - bf2f(h.y));
    h.z = f2bf(v.z); l.z = f2bf(v.z - bf2f(h.z));
    h.w = f2bf(v.w); l.w = f2bf(v.w - bf2f(h.w));
    *(ushort4*)(Wh + i) = h;
    *(ushort4*)(Wl + i) = l;
}

// ---- GEMM: P[z][t][e] = sum_{k in chunk z} X[t,k] W[e,k], bf16x2 3-pass MFMA ----
// T3+T4 port: 4 phases/K-step, raw s_barrier pairs, COUNTED vmcnt (never 0 in
// main loop). Per thread per step: 4 A fp32 loads (reg) + 4 B gl_lds in flight.
// A(s+1) issued at step s-1 phase 3; B(s+1) at step s phase 0 (FIFO: A older).
//   phase 2: vmcnt(4) -> A(s+1) regs ready (B(s+1) still flying), convert+ds_write.
//   phase 3: issue A(s+2); vmcnt(4) -> B(s+1) landed (A(s+2) still flying).
// Only vmcnt(0): once at s==NSTEPS-2. Writes go to nxt only; all cur reads
// complete before the step-end barrier, and nxt's prior readers finished a
// full step earlier -> no races.
__global__ __launch_bounds__(512, 2) void gate_gemm(const float* __restrict__ X,
                                                    const unsigned short* __restrict__ Wh,
                                                    const unsigned short* __restrict__ Wl,
                                                    float* __restrict__ P) {
    __shared__ __align__(16) unsigned short Ah[2][BM * BK];    // 2 x 16 KB
    __shared__ __align__(16) unsigned short Al[2][BM * BK];
    __shared__ __align__(16) unsigned short Bh[2][NEXP * BK];
    __shared__ __align__(16) unsigned short Bl[2][NEXP * BK];  // 128 KB total

    const int t  = threadIdx.x;            // 0..511
    const int bm = blockIdx.x * BM;
    const int z  = blockIdx.y;
    const int k0 = z * KCHUNK;

    const int l  = t & 63;
    const int w  = t >> 6;                 // 0..7
    const int wr = w >> 2;                 // 0..1: row half (128 tokens)
    const int wc = w & 3;                  // 0..3: col quarter (64 experts)
    const int lm = l & 15;
    const int lq = l >> 4;                 // 16B k-slot (0..3)

    // A staging: thread t -> row t>>1 (0..255), k-half (t&1)*16
    const int ar = t >> 1;
    const float* xrow = X + (size_t)(bm + ar) * DIM + k0 + (t & 1) * 16;

#define BSTAGE(buf, step)                                                           \
    do {                                                                            \
        const int krn_ = (step) * BK;                                               \
        _Pragma("unroll")                                                           \
        for (int i_ = 0; i_ < 2; ++i_) {                                            \
            int flat_ = i_ * 512 + t;                                               \
            int e_ = flat_ >> 2, qq_ = flat_ & 3;                                   \
            const unsigned short* gh_ = Wh + (size_t)e_ * DIM + k0 + krn_ + swz4(e_, qq_) * 8; \
            const unsigned short* gl_ = Wl + (size_t)e_ * DIM + k0 + krn_ + swz4(e_, qq_) * 8; \
            __builtin_amdgcn_global_load_lds(                                       \
                (const __attribute__((address_space(1))) unsigned int*)gh_,         \
                (__attribute__((address_space(3))) unsigned int*)&Bh[buf][flat_ * 8], 16, 0, 0); \
            __builtin_amdgcn_global_load_lds(                                       \
                (const __attribute__((address_space(1))) unsigned int*)gl_,         \
                (__attribute__((address_space(3))) unsigned int*)&Bl[buf][flat_ * 8], 16, 0, 0); \
        }                                                                           \
    } while (0)

#define ACONV(buf, v0, v1, v2, v3)                                                  \
    do {                                                                            \
        float4 xa_[4] = {v0, v1, v2, v3};                                           \
        _Pragma("unroll")                                                           \
        for (int i_ = 0; i_ < 4; ++i_) {                                            \
            ushort4 h_, lo_;                                                        \
            h_.x = f2bf(xa_[i_].x); lo_.x = f2bf(xa_[i_].x - bf2f(h_.x));           \
            h_.y = f2bf(xa_[i_].y); lo_.y = f2bf(xa_[i_].y - bf2f(h_.y));           \
            h_.z = f2bf(xa_[i_].z); lo_.z = f2bf(xa_[i_].z - bf2f(h_.z));           \
            h_.w = f2bf(xa_[i_].w); lo_.w = f2bf(xa_[i_].w - bf2f(h_.w));           \
            int j_ = (t & 1) * 4 + i_;                                              \
            int idx_ = ar * BK + swz4(ar, j_ >> 1) * 8 + (j_ & 1) * 4;              \
            *(ushort4*)&Ah[buf][idx_] = h_;                                         \
            *(ushort4*)&Al[buf][idx_] = lo_;                                        \
        }                                                                           \
    } while (0)

    v4f acc[8][4] = {};
    float4 xv0, xv1, xv2, xv3;             // A(s+1) in flight across phases 0-2

    // ---- prologue ----
    {
        float4 p0 = *(const float4*)(xrow);          // A(0): 4 loads (oldest)
        float4 p1 = *(const float4*)(xrow + 4);
        float4 p2 = *(const float4*)(xrow + 8);
        float4 p3 = *(const float4*)(xrow + 12);
        BSTAGE(0, 0);                                 // B(0): 4 gl_lds
        asm volatile("s_waitcnt vmcnt(4)" ::: "memory");   // A(0) ready
        __builtin_amdgcn_sched_barrier(0);
        ACONV(0, p0, p1, p2, p3);
        xv0 = *(const float4*)(xrow + BK);            // A(1): 4 loads
        xv1 = *(const float4*)(xrow + BK + 4);
        xv2 = *(const float4*)(xrow + BK + 8);
        xv3 = *(const float4*)(xrow + BK + 12);
        asm volatile("s_waitcnt vmcnt(4)" ::: "memory");   // B(0) landed
        asm volatile("s_waitcnt lgkmcnt(0)" ::: "memory"); // own A(0) ds_writes
        __builtin_amdgcn_sched_barrier(0);
        __builtin_amdgcn_s_barrier();
    }

    int cur = 0;
    for (int s = 0; s < NSTEPS; ++s) {
        const int nxt = cur ^ 1;
        const bool pf = (s + 1 < NSTEPS);

        short8 bh[4], bl[4];
#pragma unroll
        for (int q = 0; q < 4; ++q) {
            // ---- pre-barrier: ds_reads for this phase ----
            if (q == 0) {
#pragma unroll
                for (int c = 0; c < 4; ++c) {
                    int e = wc * 64 + c * 16 + lm;
                    bh[c] = *(const short8*)&Bh[cur][e * BK + swz4(e, lq) * 8];
                    bl[c] = *(const short8*)&Bl[cur][e * BK + swz4(e, lq) * 8];
                }
            }
            const int m0 = wr * 128 + (2 * q) * 16 + lm;
            const int m1 = m0 + 16;
            short8 a0h = *(const short8*)&Ah[cur][m0 * BK + swz4(m0, lq) * 8];
            short8 a0l = *(const short8*)&Al[cur][m0 * BK + swz4(m0, lq) * 8];
            short8 a1h = *(const short8*)&Ah[cur][m1 * BK + swz4(m1, lq) * 8];
            short8 a1l = *(const short8*)&Al[cur][m1 * BK + swz4(m1, lq) * 8];

            // ---- pre-barrier: staging piece ----
            if (q == 0 && pf) {
                BSTAGE(nxt, s + 1);                   // B(s+1): 4 gl_lds -> nxt
            }
            if (q == 2 && pf) {
                asm volatile("s_waitcnt vmcnt(4)" ::: "memory");  // A(s+1) ready
                __builtin_amdgcn_sched_barrier(0);
                ACONV(nxt, xv0, xv1, xv2, xv3);       // convert + ds_write -> nxt
            }
            if (q == 3) {
                if (s + 2 < NSTEPS) {                 // A(s+2): keep 4 in flight
                    const float* xn = xrow + (s + 2) * BK;
                    xv0 = *(const float4*)(xn);
                    xv1 = *(const float4*)(xn + 4);
                    xv2 = *(const float4*)(xn + 8);
                    xv3 = *(const float4*)(xn + 12);
                    asm volatile("s_waitcnt vmcnt(4)" ::: "memory"); // B(s+1) landed
                    __builtin_amdgcn_sched_barrier(0);
                } else if (pf) {                      // s == NSTEPS-2: one full drain
                    asm volatile("s_waitcnt vmcnt(0)" ::: "memory");
                    __builtin_amdgcn_sched_barrier(0);
                }
            }

            __builtin_amdgcn_s_barrier();
            asm volatile("s_waitcnt lgkmcnt(0)" ::: "memory");
            __builtin_amdgcn_sched_barrier(0);        // rule #18
            __builtin_amdgcn_s_setprio(1);
#pragma unroll
            for (int c = 0; c < 4; ++c) {
                acc[2 * q][c] = __builtin_amdgcn_mfma_f32_16x16x32_bf16(a0h, bh[c], acc[2 * q][c], 0, 0, 0);
                acc[2 * q][c] = __builtin_amdgcn_mfma_f32_16x16x32_bf16(a0h, bl[c], acc[2 * q][c], 0, 0, 0);
                acc[2 * q][c] = __builtin_amdgcn_mfma_f32_16x16x32_bf16(a0l, bh[c], acc[2 * q][c], 0, 0, 0);
            }
#pragma unroll
            for (int c = 0; c < 4; ++c) {
                acc[2 * q + 1][c] = __builtin_amdgcn_mfma_f32_16x16x32_bf16(a1h, bh[c], acc[2 * q + 1][c], 0, 0, 0);
                acc[2 * q + 1][c] = __builtin_amdgcn_mfma_f32_16x16x32_bf16(a1h, bl[c], acc[2 * q + 1][c], 0, 0, 0);
                acc[2 * q + 1][c] = __builtin_amdgcn_mfma_f32_16x16x32_bf16(a1l, bh[c], acc[2 * q + 1][c], 0, 0, 0);
            }
            __builtin_amdgcn_s_setprio(0);
            __builtin_amdgcn_s_barrier();
        }
        cur = nxt;
    }

    // epilogue: C/D layout col=lane&15, row=lq*4+reg (verified m89/m91)
    float* Pb = P + ((size_t)z * NTOK + bm) * NEXP;
#pragma unroll
    for (int r = 0; r < 8; ++r)
#pragma unroll
        for (int c = 0; c < 4; ++c)
#pragma unroll
            for (int g = 0; g < 4; ++g)
                Pb[(size_t)(wr * 128 + r * 16 + lq * 4 + g) * NEXP + wc * 64 + c * 16 + lm] = acc[r][c][g];
#undef BSTAGE
#undef ACONV
}

// ---- fused reduce (4 partials, fixed order) + routing: one wave per token ----
__global__ __launch_bounds__(256) void gate_route(const float* __restrict__ P,
                                                  float* __restrict__ outw,
                                                  float* __restrict__ outi) {
    const int lane = threadIdx.x & 63;
    const int tok  = (blockIdx.x * blockDim.x + threadIdx.x) >> 6;
    if (tok >= NTOK) return;

    float l[4] = {0.f, 0.f, 0.f, 0.f};
#pragma unroll
    for (int z = 0; z < NSPLIT; ++z) {   // fixed order: deterministic across runs
        float4 v = *(const float4*)(P + ((size_t)z * NTOK + tok) * NEXP + lane * 4);
        l[0] += v.x; l[1] += v.y; l[2] += v.z; l[3] += v.w;
    }

    float lmax = fmaxf(fmaxf(l[0], l[1]), fmaxf(l[2], l[3]));
    float m = lmax;
#pragma unroll
    for (int o = 32; o; o >>= 1) m = fmaxf(m, __shfl_xor(m, o));

    float s = __expf(l[0] - m) + __expf(l[1] - m) + __expf(l[2] - m) + __expf(l[3] - m);
#pragma unroll
    for (int o = 32; o; o >>= 1) s += __shfl_xor(s, o);

    float gm = lmax;
#pragma unroll
    for (int o = 4; o; o >>= 1) gm = fmaxf(gm, __shfl_xor(gm, o));

    const int g = lane >> 3;
    int rank = 0;
#pragma unroll
    for (int gg = 0; gg < 8; ++gg) {
        float vg = __shfl(gm, gg * 8);
        rank += (vg > gm) || (vg == gm && gg < g);
    }
    const bool allowed = rank < TOPKG;

    float mv[4];
#pragma unroll
    for (int j = 0; j < 4; ++j) mv[j] = allowed ? l[j] : -INFINITY;

    float wsel = 0.0f;
    int   isel = 0;

    for (int k = 0; k < TOPK; ++k) {
        float bv = mv[0];
        int   bi = lane * 4;
        if (mv[1] > bv) { bv = mv[1]; bi = lane * 4 + 1; }
        if (mv[2] > bv) { bv = mv[2]; bi = lane * 4 + 2; }
        if (mv[3] > bv) { bv = mv[3]; bi = lane * 4 + 3; }
#pragma unroll
        for (int o = 32; o; o >>= 1) {
            float ov = __shfl_xor(bv, o);
            int   oi = __shfl_xor(bi, o);
            if (ov > bv || (ov == bv && oi < bi)) { bv = ov; bi = oi; }
        }
        if (lane == k) { wsel = __expf(bv - m) / s; isel = bi; }
        if ((bi >> 2) == lane) mv[bi & 3] = -INFINITY;
    }

    if (lane < TOPK) {
        outw[(size_t)tok * TOPK + lane] = wsel;
        outi[(size_t)tok * TOPK + lane] = (float)isel;
    }
}

extern "C" void kernel_launch(void* const* d_in, const int* in_sizes, int n_in,
                              void* d_out, int out_size, void* d_ws, size_t ws_size,
                              hipStream_t stream) {
    const float* x  = (const float*)d_in[0];   // [16384, 4096]
    const float* wt = (const float*)d_in[1];   // [256, 4096]

    // ws layout: partials [4][16384][256] f32 (64 MB) | Wh (2 MB) | Wl (2 MB)
    float* P = (float*)d_ws;
    unsigned short* Wh = (unsigned short*)((char*)d_ws + (size_t)NSPLIT * NTOK * NEXP * 4);
    unsigned short* Wl = Wh + (size_t)NEXP * DIM;

    float* outw = (float*)d_out;
    float* outi = (float*)d_out + (size_t)NTOK * TOPK;

    wprep<<<(NEXP * DIM) / (256 * 4), 256, 0, stream>>>(wt, Wh, Wl);

    dim3 ggrid(NTOK / BM, NSPLIT);   // (64, 4) = 256 blocks, 1/CU, 8 waves
    gate_gemm<<<ggrid, 512, 0, stream>>>(x, Wh, Wl, P);

    gate_route<<<(NTOK * 64) / 256, 256, 0, stream>>>(P, outw, outi);
}